// Round 8
// baseline (316.019 us; speedup 1.0000x reference)
//
#include <hip/hip_runtime.h>
#include <hip/hip_bf16.h>

constexpr int NN = 100000;
constexpr int NE = 625000;
constexpr int F  = 128;
constexpr int C  = 32;
constexpr int CQ  = C / 4;  // 8 float4 per projected row
constexpr int NB  = (NN + 255) / 256;   // 391 scan blocks

// ---------- degree / norm ----------
__global__ void k_zero(int* __restrict__ cnt) {
    int i = blockIdx.x * blockDim.x + threadIdx.x;
    if (i < NN) cnt[i] = 0;
}

__global__ void k_count(const int* __restrict__ dstA, int* __restrict__ cnt) {
    int e = blockIdx.x * blockDim.x + threadIdx.x;
    if (e < NE) atomicAdd(&cnt[dstA[e]], 1);
}

__global__ void k_dinv(const int* __restrict__ cnt, float* __restrict__ dinv) {
    int i = blockIdx.x * blockDim.x + threadIdx.x;
    if (i < NN) dinv[i] = rsqrtf((float)(cnt[i] + 1));   // +1 self loop
}

// ---------- CSR build: two-level scan ----------
__global__ __launch_bounds__(256) void k_blocksum(const int* __restrict__ cnt,
                                                  int* __restrict__ blocksums) {
    int idx = blockIdx.x * 256 + threadIdx.x;
    int v = (idx < NN) ? cnt[idx] : 0;
    #pragma unroll
    for (int off = 32; off; off >>= 1) v += __shfl_down(v, off, 64);
    __shared__ int ws[4];
    int lane = threadIdx.x & 63, wid = threadIdx.x >> 6;
    if (lane == 0) ws[wid] = v;
    __syncthreads();
    if (threadIdx.x == 0)
        blocksums[blockIdx.x] = ws[0] + ws[1] + ws[2] + ws[3];
}

__global__ __launch_bounds__(512) void k_scanB(const int* __restrict__ blocksums,
                                               int* __restrict__ blockoff,
                                               int* __restrict__ rowptr) {
    __shared__ int s[512];
    int t = threadIdx.x;
    s[t] = (t < NB) ? blocksums[t] : 0;
    __syncthreads();
    for (int off = 1; off < 512; off <<= 1) {
        int v = (t >= off) ? s[t - off] : 0;
        __syncthreads();
        s[t] += v;
        __syncthreads();
    }
    if (t < NB) blockoff[t] = (t == 0) ? 0 : s[t - 1];
    if (t == NB - 1) rowptr[NN] = s[t];
}

__global__ __launch_bounds__(256) void k_scanC(const int* __restrict__ cnt,
                                               const int* __restrict__ blockoff,
                                               int* __restrict__ rowptr,
                                               int* __restrict__ cursor) {
    __shared__ int s[256];
    int t = threadIdx.x;
    int idx = blockIdx.x * 256 + t;
    int val = (idx < NN) ? cnt[idx] : 0;
    s[t] = val;
    __syncthreads();
    for (int off = 1; off < 256; off <<= 1) {
        int v = (t >= off) ? s[t - off] : 0;
        __syncthreads();
        s[t] += v;
        __syncthreads();
    }
    if (idx < NN) {
        int r = blockoff[blockIdx.x] + s[t] - val;
        rowptr[idx] = r;
        cursor[idx] = r;
    }
}

__global__ void k_fill(const int* __restrict__ srcA, const int* __restrict__ dstA,
                       int* __restrict__ cursor, int* __restrict__ col) {
    int e = blockIdx.x * blockDim.x + threadIdx.x;
    if (e >= NE) return;
    int s = srcA[e], d = dstA[e];
    int pos = atomicAdd(&cursor[d], 1);
    col[pos] = s;
}

// ---------- projection + prescale: u0 = dinv ⊙ (x @ W^T) ----------
// thread = (node, class-pair): 1.6M threads (~97 waves/CU demand -> full occupancy).
// Per iter: 1 broadcast x-float4 (16 lanes share addr) + 2 L1-hot W-float4 + 8 FMA.
__global__ __launch_bounds__(256) void k_proj(const float* __restrict__ x,
                                              const float* __restrict__ W,
                                              const float* __restrict__ dinv,
                                              float* __restrict__ u0) {
    int t = blockIdx.x * 256 + threadIdx.x;
    if (t >= NN * 16) return;
    int node = t >> 4;
    int cp   = t & 15;           // classes 2cp, 2cp+1

    const float4* xr  = (const float4*)(x + (size_t)node * F);
    const float4* wr0 = (const float4*)(W + (size_t)(2 * cp) * F);
    const float4* wr1 = (const float4*)(W + (size_t)(2 * cp + 1) * F);

    float a0 = 0.f, a1 = 0.f;
    #pragma unroll 8
    for (int q = 0; q < F / 4; ++q) {
        float4 xv = xr[q];
        float4 w0 = wr0[q], w1 = wr1[q];
        a0 += xv.x * w0.x + xv.y * w0.y + xv.z * w0.z + xv.w * w0.w;
        a1 += xv.x * w1.x + xv.y * w1.y + xv.z * w1.z + xv.w * w1.w;
    }
    float dn = dinv[node];
    *(float2*)(u0 + (size_t)node * C + 2 * cp) = make_float2(dn * a0, dn * a1);
}

// ---------- hop 1: u1[i] = dinv[i]^2 * (u0[i] + sum_e u0[col]) ----------
__global__ void k_gather(const float* __restrict__ uin, const int* __restrict__ rowptr,
                         const int* __restrict__ col, const float* __restrict__ dinv,
                         float* __restrict__ uout) {
    int t = blockIdx.x * blockDim.x + threadIdx.x;   // thread per (node, float4 chunk)
    if (t >= NN * CQ) return;
    int node = t >> 3;   // CQ = 8
    int q    = t & 7;
    float4 v = ((const float4*)uin)[node * CQ + q];  // self term
    float ax = v.x, ay = v.y, az = v.z, aw = v.w;
    int e0 = rowptr[node], e1 = rowptr[node + 1];
    for (int e = e0; e < e1; ++e) {
        int s = col[e];
        float4 u = ((const float4*)uin)[s * CQ + q];
        ax += u.x; ay += u.y; az += u.z; aw += u.w;
    }
    float dn = dinv[node];
    float c = dn * dn;
    ((float4*)uout)[node * CQ + q] = make_float4(c * ax, c * ay, c * az, c * aw);
}

// ---------- hop 2 + bias + log_softmax, thread = (node, class-quad of 8) ----------
// logits = dinv[i] * (u1[i] + sum_e u1[col]) + b
__global__ __launch_bounds__(256) void k_hop2_finish(const float* __restrict__ uin,
                                                     const int* __restrict__ rowptr,
                                                     const int* __restrict__ col,
                                                     const float* __restrict__ dinv,
                                                     const float* __restrict__ b,
                                                     float* __restrict__ out) {
    int t = blockIdx.x * 256 + threadIdx.x;
    if (t >= NN * 4) return;
    int node = t >> 2;
    int qr   = t & 3;          // classes [qr*8, qr*8+8)

    const float4* zrow = (const float4*)(uin + (size_t)node * C) + qr * 2;
    float4 a0 = zrow[0], a1 = zrow[1];            // self term

    int e0 = rowptr[node], e1 = rowptr[node + 1];
    for (int e = e0; e < e1; ++e) {
        int s = col[e];             // 4 lanes same address -> broadcast
        const float4* u = (const float4*)(uin + (size_t)s * C) + qr * 2;
        float4 u0 = u[0], u1 = u[1];
        a0.x += u0.x; a0.y += u0.y; a0.z += u0.z; a0.w += u0.w;
        a1.x += u1.x; a1.y += u1.y; a1.z += u1.z; a1.w += u1.w;
    }

    float dn = dinv[node];
    float4 b0 = ((const float4*)b)[qr * 2];
    float4 b1 = ((const float4*)b)[qr * 2 + 1];
    float v[8] = { dn * a0.x + b0.x, dn * a0.y + b0.y, dn * a0.z + b0.z, dn * a0.w + b0.w,
                   dn * a1.x + b1.x, dn * a1.y + b1.y, dn * a1.z + b1.z, dn * a1.w + b1.w };

    float m = v[0];
    #pragma unroll
    for (int c = 1; c < 8; ++c) m = fmaxf(m, v[c]);
    m = fmaxf(m, __shfl_xor(m, 1, 64));     // reduce across the node's 4 lanes
    m = fmaxf(m, __shfl_xor(m, 2, 64));
    float s = 0.f;
    #pragma unroll
    for (int c = 0; c < 8; ++c) s += expf(v[c] - m);
    s += __shfl_xor(s, 1, 64);
    s += __shfl_xor(s, 2, 64);
    float lse = m + logf(s);

    float4* op = (float4*)(out + (size_t)node * C + qr * 8);
    op[0] = make_float4(v[0]-lse, v[1]-lse, v[2]-lse, v[3]-lse);
    op[1] = make_float4(v[4]-lse, v[5]-lse, v[6]-lse, v[7]-lse);
}

extern "C" void kernel_launch(void* const* d_in, const int* in_sizes, int n_in,
                              void* d_out, int out_size, void* d_ws, size_t ws_size,
                              hipStream_t stream) {
    const float* x  = (const float*)d_in[0];
    const int*   ei = (const int*)d_in[1];     // [2, NE] int32
    const float* W  = (const float*)d_in[2];
    const float* b  = (const float*)d_in[3];
    float* out = (float*)d_out;

    const int* srcA = ei;
    const int* dstA = ei + NE;

    char* p = (char*)d_ws;
    auto alloc = [&](size_t bytes) { char* r = p; p += (bytes + 255) & ~(size_t)255; return r; };
    int*   cnt       = (int*)  alloc(sizeof(int) * NN);
    float* dinv      = (float*)alloc(sizeof(float) * NN);
    int*   rowptr    = (int*)  alloc(sizeof(int) * (NN + 1));
    int*   cursor    = (int*)  alloc(sizeof(int) * NN);
    int*   blocksums = (int*)  alloc(sizeof(int) * NB);
    int*   blockoff  = (int*)  alloc(sizeof(int) * NB);
    int*   col       = (int*)  alloc(sizeof(int) * NE);
    float* u0        = (float*)alloc(sizeof(float) * (size_t)NN * C);
    float* u1        = (float*)alloc(sizeof(float) * (size_t)NN * C);

    // norm + CSR build
    k_zero    <<<(NN + 255) / 256, 256, 0, stream>>>(cnt);
    k_count   <<<(NE + 255) / 256, 256, 0, stream>>>(dstA, cnt);
    k_dinv    <<<(NN + 255) / 256, 256, 0, stream>>>(cnt, dinv);
    k_blocksum<<<NB, 256, 0, stream>>>(cnt, blocksums);
    k_scanB   <<<1, 512, 0, stream>>>(blocksums, blockoff, rowptr);
    k_scanC   <<<NB, 256, 0, stream>>>(cnt, blockoff, rowptr, cursor);
    k_fill    <<<(NE + 255) / 256, 256, 0, stream>>>(srcA, dstA, cursor, col);

    // projection + prescale: u0 = dinv ⊙ (x W^T)
    k_proj<<<(NN * 16 + 255) / 256, 256, 0, stream>>>(x, W, dinv, u0);

    // hop 1: u0 -> u1 (prescaled domain)
    k_gather<<<(NN * CQ + 255) / 256, 256, 0, stream>>>(u0, rowptr, col, dinv, u1);
    // hop 2 fused with bias + log_softmax: u1 -> out
    k_hop2_finish<<<(NN * 4 + 255) / 256, 256, 0, stream>>>(u1, rowptr, col, dinv, b, out);
}

// Round 9
// 270.819 us; speedup vs baseline: 1.1669x; 1.1669x over previous
//
#include <hip/hip_runtime.h>
#include <hip/hip_bf16.h>

constexpr int NN = 100000;
constexpr int NE = 625000;
constexpr int F  = 128;
constexpr int C  = 32;
constexpr int CQ  = C / 4;  // 8 float4 per projected row
constexpr int NB  = (NN + 255) / 256;   // 391 scan blocks

// ---------- degree / norm ----------
__global__ void k_zero(int* __restrict__ cnt) {
    int i = blockIdx.x * blockDim.x + threadIdx.x;
    if (i < NN) cnt[i] = 0;
}

__global__ void k_count(const int* __restrict__ dstA, int* __restrict__ cnt) {
    int e = blockIdx.x * blockDim.x + threadIdx.x;
    if (e < NE) atomicAdd(&cnt[dstA[e]], 1);
}

__global__ void k_dinv(const int* __restrict__ cnt, float* __restrict__ dinv) {
    int i = blockIdx.x * blockDim.x + threadIdx.x;
    if (i < NN) dinv[i] = rsqrtf((float)(cnt[i] + 1));   // +1 self loop
}

// ---------- CSR build: two-level scan ----------
__global__ __launch_bounds__(256) void k_blocksum(const int* __restrict__ cnt,
                                                  int* __restrict__ blocksums) {
    int idx = blockIdx.x * 256 + threadIdx.x;
    int v = (idx < NN) ? cnt[idx] : 0;
    #pragma unroll
    for (int off = 32; off; off >>= 1) v += __shfl_down(v, off, 64);
    __shared__ int ws[4];
    int lane = threadIdx.x & 63, wid = threadIdx.x >> 6;
    if (lane == 0) ws[wid] = v;
    __syncthreads();
    if (threadIdx.x == 0)
        blocksums[blockIdx.x] = ws[0] + ws[1] + ws[2] + ws[3];
}

__global__ __launch_bounds__(512) void k_scanB(const int* __restrict__ blocksums,
                                               int* __restrict__ blockoff,
                                               int* __restrict__ rowptr) {
    __shared__ int s[512];
    int t = threadIdx.x;
    s[t] = (t < NB) ? blocksums[t] : 0;
    __syncthreads();
    for (int off = 1; off < 512; off <<= 1) {
        int v = (t >= off) ? s[t - off] : 0;
        __syncthreads();
        s[t] += v;
        __syncthreads();
    }
    if (t < NB) blockoff[t] = (t == 0) ? 0 : s[t - 1];
    if (t == NB - 1) rowptr[NN] = s[t];
}

__global__ __launch_bounds__(256) void k_scanC(const int* __restrict__ cnt,
                                               const int* __restrict__ blockoff,
                                               int* __restrict__ rowptr,
                                               int* __restrict__ cursor) {
    __shared__ int s[256];
    int t = threadIdx.x;
    int idx = blockIdx.x * 256 + t;
    int val = (idx < NN) ? cnt[idx] : 0;
    s[t] = val;
    __syncthreads();
    for (int off = 1; off < 256; off <<= 1) {
        int v = (t >= off) ? s[t - off] : 0;
        __syncthreads();
        s[t] += v;
        __syncthreads();
    }
    if (idx < NN) {
        int r = blockoff[blockIdx.x] + s[t] - val;
        rowptr[idx] = r;
        cursor[idx] = r;
    }
}

__global__ void k_fill(const int* __restrict__ srcA, const int* __restrict__ dstA,
                       int* __restrict__ cursor, int* __restrict__ col) {
    int e = blockIdx.x * blockDim.x + threadIdx.x;
    if (e >= NE) return;
    int s = srcA[e], d = dstA[e];
    int pos = atomicAdd(&cursor[d], 1);
    col[pos] = s;
}

// ---------- projection + prescale: u0 = dinv ⊙ (x @ W^T) ----------
// thread = (node-pair, k-quarter). W in LDS (wave-uniform-ish broadcast reads,
// conflict-free: banks {4*kq + 16*s}). Each W read reused across 2 nodes.
// x loads: q = kq + 4*s -> 4 lanes of a node read 64 contiguous bytes.
__global__ __launch_bounds__(256) void k_proj(const float* __restrict__ x,
                                              const float* __restrict__ W,
                                              const float* __restrict__ dinv,
                                              float* __restrict__ u0) {
    __shared__ float Ws[C * F];   // 16 KB, [class][feat], unpadded
    for (int i = threadIdx.x; i < C * F; i += 256) Ws[i] = W[i];
    __syncthreads();

    int t  = blockIdx.x * 256 + threadIdx.x;
    int kq = t & 3;                // k-quarter: q = kq, kq+4, ..., kq+28
    int np = t >> 2;               // node-pair
    int n0 = np * 2, n1 = n0 + 1;
    bool v0 = n0 < NN, v1 = n1 < NN;
    int m0 = v0 ? n0 : NN - 1;     // clamped (safe loads, no OOB)
    int m1 = v1 ? n1 : NN - 1;

    const float4* xr0 = (const float4*)(x + (size_t)m0 * F);
    const float4* xr1 = (const float4*)(x + (size_t)m1 * F);

    float acc0[C], acc1[C];
    #pragma unroll
    for (int c = 0; c < C; ++c) { acc0[c] = 0.f; acc1[c] = 0.f; }

    #pragma unroll
    for (int s = 0; s < 8; ++s) {
        int q = kq + 4 * s;        // float4 index in the 128-float row
        float4 xv0 = xr0[q];
        float4 xv1 = xr1[q];
        #pragma unroll
        for (int c = 0; c < C; ++c) {
            float4 w = ((const float4*)Ws)[c * (F / 4) + q];
            acc0[c] += xv0.x * w.x + xv0.y * w.y + xv0.z * w.z + xv0.w * w.w;
            acc1[c] += xv1.x * w.x + xv1.y * w.y + xv1.z * w.z + xv1.w * w.w;
        }
    }

    // reduce over the 4 k-quarter lanes (lane bits 0-1)
    #pragma unroll
    for (int c = 0; c < C; ++c) {
        acc0[c] += __shfl_xor(acc0[c], 1, 64);
        acc0[c] += __shfl_xor(acc0[c], 2, 64);
        acc1[c] += __shfl_xor(acc1[c], 1, 64);
        acc1[c] += __shfl_xor(acc1[c], 2, 64);
    }

    // lane kq writes classes [8kq, 8kq+8) for both nodes (coalesced 32B/lane)
    int cb = kq * 8;
    if (v0) {
        float dn = dinv[n0];
        float4* op = (float4*)(u0 + (size_t)n0 * C + cb);
        op[0] = make_float4(dn*acc0[cb+0], dn*acc0[cb+1], dn*acc0[cb+2], dn*acc0[cb+3]);
        op[1] = make_float4(dn*acc0[cb+4], dn*acc0[cb+5], dn*acc0[cb+6], dn*acc0[cb+7]);
    }
    if (v1) {
        float dn = dinv[n1];
        float4* op = (float4*)(u0 + (size_t)n1 * C + cb);
        op[0] = make_float4(dn*acc1[cb+0], dn*acc1[cb+1], dn*acc1[cb+2], dn*acc1[cb+3]);
        op[1] = make_float4(dn*acc1[cb+4], dn*acc1[cb+5], dn*acc1[cb+6], dn*acc1[cb+7]);
    }
}

// ---------- hop 1: u1[i] = dinv[i]^2 * (u0[i] + sum_e u0[col]) ----------
__global__ void k_gather(const float* __restrict__ uin, const int* __restrict__ rowptr,
                         const int* __restrict__ col, const float* __restrict__ dinv,
                         float* __restrict__ uout) {
    int t = blockIdx.x * blockDim.x + threadIdx.x;   // thread per (node, float4 chunk)
    if (t >= NN * CQ) return;
    int node = t >> 3;   // CQ = 8
    int q    = t & 7;
    float4 v = ((const float4*)uin)[node * CQ + q];  // self term
    float ax = v.x, ay = v.y, az = v.z, aw = v.w;
    int e0 = rowptr[node], e1 = rowptr[node + 1];
    for (int e = e0; e < e1; ++e) {
        int s = col[e];
        float4 u = ((const float4*)uin)[s * CQ + q];
        ax += u.x; ay += u.y; az += u.z; aw += u.w;
    }
    float dn = dinv[node];
    float c = dn * dn;
    ((float4*)uout)[node * CQ + q] = make_float4(c * ax, c * ay, c * az, c * aw);
}

// ---------- hop 2 + bias + log_softmax, thread = (node, class-quad of 8) ----------
// logits = dinv[i] * (u1[i] + sum_e u1[col]) + b
__global__ __launch_bounds__(256) void k_hop2_finish(const float* __restrict__ uin,
                                                     const int* __restrict__ rowptr,
                                                     const int* __restrict__ col,
                                                     const float* __restrict__ dinv,
                                                     const float* __restrict__ b,
                                                     float* __restrict__ out) {
    int t = blockIdx.x * 256 + threadIdx.x;
    if (t >= NN * 4) return;
    int node = t >> 2;
    int qr   = t & 3;          // classes [qr*8, qr*8+8)

    const float4* zrow = (const float4*)(uin + (size_t)node * C) + qr * 2;
    float4 a0 = zrow[0], a1 = zrow[1];            // self term

    int e0 = rowptr[node], e1 = rowptr[node + 1];
    for (int e = e0; e < e1; ++e) {
        int s = col[e];             // 4 lanes same address -> broadcast
        const float4* u = (const float4*)(uin + (size_t)s * C) + qr * 2;
        float4 u0 = u[0], u1 = u[1];
        a0.x += u0.x; a0.y += u0.y; a0.z += u0.z; a0.w += u0.w;
        a1.x += u1.x; a1.y += u1.y; a1.z += u1.z; a1.w += u1.w;
    }

    float dn = dinv[node];
    float4 b0 = ((const float4*)b)[qr * 2];
    float4 b1 = ((const float4*)b)[qr * 2 + 1];
    float v[8] = { dn * a0.x + b0.x, dn * a0.y + b0.y, dn * a0.z + b0.z, dn * a0.w + b0.w,
                   dn * a1.x + b1.x, dn * a1.y + b1.y, dn * a1.z + b1.z, dn * a1.w + b1.w };

    float m = v[0];
    #pragma unroll
    for (int c = 1; c < 8; ++c) m = fmaxf(m, v[c]);
    m = fmaxf(m, __shfl_xor(m, 1, 64));     // reduce across the node's 4 lanes
    m = fmaxf(m, __shfl_xor(m, 2, 64));
    float s = 0.f;
    #pragma unroll
    for (int c = 0; c < 8; ++c) s += expf(v[c] - m);
    s += __shfl_xor(s, 1, 64);
    s += __shfl_xor(s, 2, 64);
    float lse = m + logf(s);

    float4* op = (float4*)(out + (size_t)node * C + qr * 8);
    op[0] = make_float4(v[0]-lse, v[1]-lse, v[2]-lse, v[3]-lse);
    op[1] = make_float4(v[4]-lse, v[5]-lse, v[6]-lse, v[7]-lse);
}

extern "C" void kernel_launch(void* const* d_in, const int* in_sizes, int n_in,
                              void* d_out, int out_size, void* d_ws, size_t ws_size,
                              hipStream_t stream) {
    const float* x  = (const float*)d_in[0];
    const int*   ei = (const int*)d_in[1];     // [2, NE] int32
    const float* W  = (const float*)d_in[2];
    const float* b  = (const float*)d_in[3];
    float* out = (float*)d_out;

    const int* srcA = ei;
    const int* dstA = ei + NE;

    char* p = (char*)d_ws;
    auto alloc = [&](size_t bytes) { char* r = p; p += (bytes + 255) & ~(size_t)255; return r; };
    int*   cnt       = (int*)  alloc(sizeof(int) * NN);
    float* dinv      = (float*)alloc(sizeof(float) * NN);
    int*   rowptr    = (int*)  alloc(sizeof(int) * (NN + 1));
    int*   cursor    = (int*)  alloc(sizeof(int) * NN);
    int*   blocksums = (int*)  alloc(sizeof(int) * NB);
    int*   blockoff  = (int*)  alloc(sizeof(int) * NB);
    int*   col       = (int*)  alloc(sizeof(int) * NE);
    float* u0        = (float*)alloc(sizeof(float) * (size_t)NN * C);
    float* u1        = (float*)alloc(sizeof(float) * (size_t)NN * C);

    // norm + CSR build
    k_zero    <<<(NN + 255) / 256, 256, 0, stream>>>(cnt);
    k_count   <<<(NE + 255) / 256, 256, 0, stream>>>(dstA, cnt);
    k_dinv    <<<(NN + 255) / 256, 256, 0, stream>>>(cnt, dinv);
    k_blocksum<<<NB, 256, 0, stream>>>(cnt, blocksums);
    k_scanB   <<<1, 512, 0, stream>>>(blocksums, blockoff, rowptr);
    k_scanC   <<<NB, 256, 0, stream>>>(cnt, blockoff, rowptr, cursor);
    k_fill    <<<(NE + 255) / 256, 256, 0, stream>>>(srcA, dstA, cursor, col);

    // projection + prescale: u0 = dinv ⊙ (x W^T)
    int pthreads = ((NN + 1) / 2) * 4;               // 200000
    k_proj<<<(pthreads + 255) / 256, 256, 0, stream>>>(x, W, dinv, u0);

    // hop 1: u0 -> u1 (prescaled domain)
    k_gather<<<(NN * CQ + 255) / 256, 256, 0, stream>>>(u0, rowptr, col, dinv, u1);
    // hop 2 fused with bias + log_softmax: u1 -> out
    k_hop2_finish<<<(NN * 4 + 255) / 256, 256, 0, stream>>>(u1, rowptr, col, dinv, b, out);
}

// Round 10
// 179.937 us; speedup vs baseline: 1.7563x; 1.5051x over previous
//
#include <hip/hip_runtime.h>
#include <hip/hip_bf16.h>

constexpr int NN = 100000;
constexpr int NE = 625000;
constexpr int F  = 128;
constexpr int C  = 32;
constexpr int CQ  = C / 4;  // 8 float4 per projected row
constexpr int NB  = (NN + 255) / 256;   // 391 scan blocks

// ---------- degree / norm ----------
__global__ void k_zero(int* __restrict__ cnt) {
    int i = blockIdx.x * blockDim.x + threadIdx.x;
    if (i < NN) cnt[i] = 0;
}

__global__ void k_count(const int* __restrict__ dstA, int* __restrict__ cnt) {
    int e = blockIdx.x * blockDim.x + threadIdx.x;
    if (e < NE) atomicAdd(&cnt[dstA[e]], 1);
}

__global__ void k_dinv(const int* __restrict__ cnt, float* __restrict__ dinv) {
    int i = blockIdx.x * blockDim.x + threadIdx.x;
    if (i < NN) dinv[i] = rsqrtf((float)(cnt[i] + 1));   // +1 self loop
}

// ---------- CSR build: two-level scan ----------
__global__ __launch_bounds__(256) void k_blocksum(const int* __restrict__ cnt,
                                                  int* __restrict__ blocksums) {
    int idx = blockIdx.x * 256 + threadIdx.x;
    int v = (idx < NN) ? cnt[idx] : 0;
    #pragma unroll
    for (int off = 32; off; off >>= 1) v += __shfl_down(v, off, 64);
    __shared__ int ws[4];
    int lane = threadIdx.x & 63, wid = threadIdx.x >> 6;
    if (lane == 0) ws[wid] = v;
    __syncthreads();
    if (threadIdx.x == 0)
        blocksums[blockIdx.x] = ws[0] + ws[1] + ws[2] + ws[3];
}

__global__ __launch_bounds__(512) void k_scanB(const int* __restrict__ blocksums,
                                               int* __restrict__ blockoff,
                                               int* __restrict__ rowptr) {
    __shared__ int s[512];
    int t = threadIdx.x;
    s[t] = (t < NB) ? blocksums[t] : 0;
    __syncthreads();
    for (int off = 1; off < 512; off <<= 1) {
        int v = (t >= off) ? s[t - off] : 0;
        __syncthreads();
        s[t] += v;
        __syncthreads();
    }
    if (t < NB) blockoff[t] = (t == 0) ? 0 : s[t - 1];
    if (t == NB - 1) rowptr[NN] = s[t];
}

__global__ __launch_bounds__(256) void k_scanC(const int* __restrict__ cnt,
                                               const int* __restrict__ blockoff,
                                               int* __restrict__ rowptr,
                                               int* __restrict__ cursor) {
    __shared__ int s[256];
    int t = threadIdx.x;
    int idx = blockIdx.x * 256 + t;
    int val = (idx < NN) ? cnt[idx] : 0;
    s[t] = val;
    __syncthreads();
    for (int off = 1; off < 256; off <<= 1) {
        int v = (t >= off) ? s[t - off] : 0;
        __syncthreads();
        s[t] += v;
        __syncthreads();
    }
    if (idx < NN) {
        int r = blockoff[blockIdx.x] + s[t] - val;
        rowptr[idx] = r;
        cursor[idx] = r;
    }
}

__global__ void k_fill(const int* __restrict__ srcA, const int* __restrict__ dstA,
                       int* __restrict__ cursor, int* __restrict__ col) {
    int e = blockIdx.x * blockDim.x + threadIdx.x;
    if (e >= NE) return;
    int s = srcA[e], d = dstA[e];
    int pos = atomicAdd(&cursor[d], 1);
    col[pos] = s;
}

// ---------- projection + prescale: u0 = dinv ⊙ (x @ W^T) ----------
// thread = (node-pair, class-half, k-half): 200k threads, acc[2][16] = 32 VGPRs.
// W in LDS with XOR swizzle (class-half groups hit disjoint bank quads; the
// 2-way k-half alias is free). FMA:LDS-read = 8:1; each W read reused x2 nodes.
__global__ __launch_bounds__(256) void k_proj(const float* __restrict__ x,
                                              const float* __restrict__ W,
                                              const float* __restrict__ dinv,
                                              float* __restrict__ u0) {
    __shared__ float4 Ws[C * 32];   // 16 KB; f4 idx = cls*32 + (q ^ ((cls>>4)<<2))
    {
        const float4* W4 = (const float4*)W;
        for (int i = threadIdx.x; i < C * 32; i += 256) {
            int cls = i >> 5, q = i & 31;
            Ws[cls * 32 + (q ^ ((cls >> 4) << 2))] = W4[i];
        }
    }
    __syncthreads();

    int t = blockIdx.x * 256 + threadIdx.x;
    if (t >= (NN / 2) * 4) return;     // 200000; whole waves only (200000 % 64 == 0... guard ok)
    int kh = t & 1;                    // k-half (lane bit 0 -> shfl_xor 1 reduce)
    int ch = (t >> 1) & 1;             // class-half
    int np = t >> 2;                   // node pair
    int n0 = np * 2, n1 = n0 + 1;

    const float4* xr0 = (const float4*)(x + (size_t)n0 * F);
    const float4* xr1 = (const float4*)(x + (size_t)n1 * F);

    float acc0[16], acc1[16];
    #pragma unroll
    for (int c = 0; c < 16; ++c) { acc0[c] = 0.f; acc1[c] = 0.f; }

    const int qbase = kh * 16;
    const int cbase = ch * 16;
    const int xorv  = ch << 2;         // swizzle for this class-half

    #pragma unroll
    for (int s = 0; s < 16; ++s) {
        int q = qbase + s;
        float4 xv0 = xr0[q];
        float4 xv1 = xr1[q];
        #pragma unroll
        for (int c = 0; c < 16; ++c) {
            float4 w = Ws[(cbase + c) * 32 + (q ^ xorv)];
            acc0[c] += xv0.x * w.x + xv0.y * w.y + xv0.z * w.z + xv0.w * w.w;
            acc1[c] += xv1.x * w.x + xv1.y * w.y + xv1.z * w.z + xv1.w * w.w;
        }
    }

    // reduce over the two k-halves (lane bit 0)
    #pragma unroll
    for (int c = 0; c < 16; ++c) {
        acc0[c] += __shfl_xor(acc0[c], 1, 64);
        acc1[c] += __shfl_xor(acc1[c], 1, 64);
    }

    // lane kh=0 writes node n0, lane kh=1 writes node n1 (64 B each)
    if (kh == 0) {
        float dn = dinv[n0];
        float4* op = (float4*)(u0 + (size_t)n0 * C + cbase);
        op[0] = make_float4(dn*acc0[0],  dn*acc0[1],  dn*acc0[2],  dn*acc0[3]);
        op[1] = make_float4(dn*acc0[4],  dn*acc0[5],  dn*acc0[6],  dn*acc0[7]);
        op[2] = make_float4(dn*acc0[8],  dn*acc0[9],  dn*acc0[10], dn*acc0[11]);
        op[3] = make_float4(dn*acc0[12], dn*acc0[13], dn*acc0[14], dn*acc0[15]);
    } else {
        float dn = dinv[n1];
        float4* op = (float4*)(u0 + (size_t)n1 * C + cbase);
        op[0] = make_float4(dn*acc1[0],  dn*acc1[1],  dn*acc1[2],  dn*acc1[3]);
        op[1] = make_float4(dn*acc1[4],  dn*acc1[5],  dn*acc1[6],  dn*acc1[7]);
        op[2] = make_float4(dn*acc1[8],  dn*acc1[9],  dn*acc1[10], dn*acc1[11]);
        op[3] = make_float4(dn*acc1[12], dn*acc1[13], dn*acc1[14], dn*acc1[15]);
    }
}

// ---------- hop 1: u1[i] = dinv[i]^2 * (u0[i] + sum_e u0[col]) ----------
__global__ void k_gather(const float* __restrict__ uin, const int* __restrict__ rowptr,
                         const int* __restrict__ col, const float* __restrict__ dinv,
                         float* __restrict__ uout) {
    int t = blockIdx.x * blockDim.x + threadIdx.x;   // thread per (node, float4 chunk)
    if (t >= NN * CQ) return;
    int node = t >> 3;   // CQ = 8
    int q    = t & 7;
    float4 v = ((const float4*)uin)[node * CQ + q];  // self term
    float ax = v.x, ay = v.y, az = v.z, aw = v.w;
    int e0 = rowptr[node], e1 = rowptr[node + 1];
    for (int e = e0; e < e1; ++e) {
        int s = col[e];
        float4 u = ((const float4*)uin)[s * CQ + q];
        ax += u.x; ay += u.y; az += u.z; aw += u.w;
    }
    float dn = dinv[node];
    float c = dn * dn;
    ((float4*)uout)[node * CQ + q] = make_float4(c * ax, c * ay, c * az, c * aw);
}

// ---------- hop 2 + bias + log_softmax, thread = (node, class-quad of 8) ----------
// logits = dinv[i] * (u1[i] + sum_e u1[col]) + b
__global__ __launch_bounds__(256) void k_hop2_finish(const float* __restrict__ uin,
                                                     const int* __restrict__ rowptr,
                                                     const int* __restrict__ col,
                                                     const float* __restrict__ dinv,
                                                     const float* __restrict__ b,
                                                     float* __restrict__ out) {
    int t = blockIdx.x * 256 + threadIdx.x;
    if (t >= NN * 4) return;
    int node = t >> 2;
    int qr   = t & 3;          // classes [qr*8, qr*8+8)

    const float4* zrow = (const float4*)(uin + (size_t)node * C) + qr * 2;
    float4 a0 = zrow[0], a1 = zrow[1];            // self term

    int e0 = rowptr[node], e1 = rowptr[node + 1];
    for (int e = e0; e < e1; ++e) {
        int s = col[e];             // 4 lanes same address -> broadcast
        const float4* u = (const float4*)(uin + (size_t)s * C) + qr * 2;
        float4 u0 = u[0], u1 = u[1];
        a0.x += u0.x; a0.y += u0.y; a0.z += u0.z; a0.w += u0.w;
        a1.x += u1.x; a1.y += u1.y; a1.z += u1.z; a1.w += u1.w;
    }

    float dn = dinv[node];
    float4 b0 = ((const float4*)b)[qr * 2];
    float4 b1 = ((const float4*)b)[qr * 2 + 1];
    float v[8] = { dn * a0.x + b0.x, dn * a0.y + b0.y, dn * a0.z + b0.z, dn * a0.w + b0.w,
                   dn * a1.x + b1.x, dn * a1.y + b1.y, dn * a1.z + b1.z, dn * a1.w + b1.w };

    float m = v[0];
    #pragma unroll
    for (int c = 1; c < 8; ++c) m = fmaxf(m, v[c]);
    m = fmaxf(m, __shfl_xor(m, 1, 64));     // reduce across the node's 4 lanes
    m = fmaxf(m, __shfl_xor(m, 2, 64));
    float s = 0.f;
    #pragma unroll
    for (int c = 0; c < 8; ++c) s += expf(v[c] - m);
    s += __shfl_xor(s, 1, 64);
    s += __shfl_xor(s, 2, 64);
    float lse = m + logf(s);

    float4* op = (float4*)(out + (size_t)node * C + qr * 8);
    op[0] = make_float4(v[0]-lse, v[1]-lse, v[2]-lse, v[3]-lse);
    op[1] = make_float4(v[4]-lse, v[5]-lse, v[6]-lse, v[7]-lse);
}

extern "C" void kernel_launch(void* const* d_in, const int* in_sizes, int n_in,
                              void* d_out, int out_size, void* d_ws, size_t ws_size,
                              hipStream_t stream) {
    const float* x  = (const float*)d_in[0];
    const int*   ei = (const int*)d_in[1];     // [2, NE] int32
    const float* W  = (const float*)d_in[2];
    const float* b  = (const float*)d_in[3];
    float* out = (float*)d_out;

    const int* srcA = ei;
    const int* dstA = ei + NE;

    char* p = (char*)d_ws;
    auto alloc = [&](size_t bytes) { char* r = p; p += (bytes + 255) & ~(size_t)255; return r; };
    int*   cnt       = (int*)  alloc(sizeof(int) * NN);
    float* dinv      = (float*)alloc(sizeof(float) * NN);
    int*   rowptr    = (int*)  alloc(sizeof(int) * (NN + 1));
    int*   cursor    = (int*)  alloc(sizeof(int) * NN);
    int*   blocksums = (int*)  alloc(sizeof(int) * NB);
    int*   blockoff  = (int*)  alloc(sizeof(int) * NB);
    int*   col       = (int*)  alloc(sizeof(int) * NE);
    float* u0        = (float*)alloc(sizeof(float) * (size_t)NN * C);
    float* u1        = (float*)alloc(sizeof(float) * (size_t)NN * C);

    // norm + CSR build
    k_zero    <<<(NN + 255) / 256, 256, 0, stream>>>(cnt);
    k_count   <<<(NE + 255) / 256, 256, 0, stream>>>(dstA, cnt);
    k_dinv    <<<(NN + 255) / 256, 256, 0, stream>>>(cnt, dinv);
    k_blocksum<<<NB, 256, 0, stream>>>(cnt, blocksums);
    k_scanB   <<<1, 512, 0, stream>>>(blocksums, blockoff, rowptr);
    k_scanC   <<<NB, 256, 0, stream>>>(cnt, blockoff, rowptr, cursor);
    k_fill    <<<(NE + 255) / 256, 256, 0, stream>>>(srcA, dstA, cursor, col);

    // projection + prescale: u0 = dinv ⊙ (x W^T)
    int pthreads = (NN / 2) * 4;                     // 200000
    k_proj<<<(pthreads + 255) / 256, 256, 0, stream>>>(x, W, dinv, u0);

    // hop 1: u0 -> u1 (prescaled domain)
    k_gather<<<(NN * CQ + 255) / 256, 256, 0, stream>>>(u0, rowptr, col, dinv, u1);
    // hop 2 fused with bias + log_softmax: u1 -> out
    k_hop2_finish<<<(NN * 4 + 255) / 256, 256, 0, stream>>>(u1, rowptr, col, dinv, b, out);
}